// Round 3
// baseline (102.554 us; speedup 1.0000x reference)
//
#include <hip/hip_runtime.h>
#include <hip/hip_bf16.h>

#define N_IN 4096
#define N_OUT 14336
#define TOPK 1228            // int(4096 * 0.3)
#define PF 4                 // prefetched float4 iters of W per wave (of 16)

// ---------------------------------------------------------------------------
// Fused kernel: each block (256 thr = 4 waves) redundantly computes the
// top-k mask of x (deterministic -> identical in every block), then streams
// 4 rows of W (one per wave) against the masked x held in LDS.
// The first PF float4 W-loads per wave are issued BEFORE the top-k so HBM
// streams from t=0 and the top-k VALU work hides under memory latency.
// ---------------------------------------------------------------------------
__global__ __launch_bounds__(256) void fused_topk_matvec_kernel(
    const float* __restrict__ x, const float* __restrict__ W,
    const float* __restrict__ bias, float* __restrict__ out) {
  __shared__ __align__(16) float s_x[N_IN];          // 16 KB
  __shared__ __align__(16) unsigned int s_hist[256]; // 1 KB
  __shared__ unsigned int s_pk[4];                   // prefix, krem, eqcount
  __shared__ unsigned long long s_cmask[N_IN / 64];  // tie path
  __shared__ unsigned int s_cbase[N_IN / 64];

  const int tid = threadIdx.x;
  const int wave = tid >> 6;
  const int lane = tid & 63;
  const int row = blockIdx.x * 4 + wave;

  const float4* __restrict__ x4 = reinterpret_cast<const float4*>(x);
  const float4* __restrict__ wr4 =
      reinterpret_cast<const float4*>(W + (size_t)row * N_IN);
  float4* s_x4 = reinterpret_cast<float4*>(s_x);

  // ---- issue x loads, then W prefetch (independent, fills HBM pipe) ----
  float4 xv0 = x4[0 * 256 + tid];
  float4 xv1 = x4[1 * 256 + tid];
  float4 xv2 = x4[2 * 256 + tid];
  float4 xv3 = x4[3 * 256 + tid];
  float4 w0 = wr4[0 * 64 + lane];
  float4 w1 = wr4[1 * 64 + lane];
  float4 w2 = wr4[2 * 64 + lane];
  float4 w3 = wr4[3 * 64 + lane];

  s_x4[0 * 256 + tid] = xv0;
  s_x4[1 * 256 + tid] = xv1;
  s_x4[2 * 256 + tid] = xv2;
  s_x4[3 * 256 + tid] = xv3;
  if (tid == 0) { s_pk[0] = 0u; s_pk[1] = TOPK; }
  __syncthreads();

  // ---- 4-pass radix select on abs-bit pattern (MSB byte -> LSB byte) ----
  for (int pass = 3; pass >= 0; --pass) {
    const unsigned int prefix = s_pk[0];
    const unsigned int krem = s_pk[1];
    s_hist[tid] = 0u;
    __syncthreads();

    const int shift = pass * 8;
    const unsigned int maskAbove =
        (pass == 3) ? 0u : (0xFFFFFFFFu << (shift + 8));

    for (int r = 0; r < 16; ++r) {
      const unsigned int ub =
          __float_as_uint(s_x[r * 256 + tid]) & 0x7fffffffu;
      const bool active = ((ub & maskAbove) == prefix);
      const unsigned int bucket = (ub >> shift) & 0xFFu;
      unsigned long long m = __ballot(active);
#pragma unroll
      for (int bit = 0; bit < 8; ++bit) {
        const unsigned long long vote =
            __ballot(active && ((bucket >> bit) & 1u));
        m &= ((bucket >> bit) & 1u) ? vote : ~vote;
      }
      if (active) {
        const int leader = __ffsll((unsigned long long)m) - 1;
        if (lane == leader)
          atomicAdd(&s_hist[bucket], (unsigned int)__popcll(m));
      }
    }
    __syncthreads();

    // Wave 0: 4 bins/lane + shfl suffix-scan; unique winner updates s_pk.
    if (tid < 64) {
      const unsigned int h0 = s_hist[tid * 4 + 0];
      const unsigned int h1 = s_hist[tid * 4 + 1];
      const unsigned int h2 = s_hist[tid * 4 + 2];
      const unsigned int h3 = s_hist[tid * 4 + 3];
      const unsigned int s = h0 + h1 + h2 + h3;
      unsigned int inc = s;
#pragma unroll
      for (int off = 1; off < 64; off <<= 1) {
        const unsigned int v = __shfl_down(inc, off, 64);
        if (tid + off < 64) inc += v;
      }
      const unsigned int U = inc - s;  // sum over lanes > tid
      const unsigned int C3 = U + h3;
      const unsigned int C2 = C3 + h2;
      const unsigned int C1 = C2 + h1;
      const unsigned int C0 = C1 + h0;
      const unsigned int Carr[4] = {C0, C1, C2, C3};
      const unsigned int Sarr[4] = {C1, C2, C3, U};
      const unsigned int hv[4] = {h0, h1, h2, h3};
#pragma unroll
      for (int j = 0; j < 4; ++j) {
        if (Sarr[j] < krem && krem <= Carr[j]) {
          s_pk[0] = prefix | ((unsigned int)(tid * 4 + j) << shift);
          s_pk[1] = krem - Sarr[j];
          s_pk[2] = hv[j];
        }
      }
    }
    __syncthreads();
  }

  const unsigned int t_abs = s_pk[0];  // bits of TOPK-th largest |x|
  const unsigned int need = s_pk[1];   // # of ==t_abs elems to take (>=1)
  const unsigned int eqc = s_pk[2];    // total # of elems ==t_abs

  // ---- zero the non-selected entries of s_x ----
  if (eqc == need) {  // no tie ranking required (the overwhelming case)
    for (int r = 0; r < 16; ++r) {
      const int i = r * 256 + tid;
      if ((__float_as_uint(s_x[i]) & 0x7fffffffu) < t_abs) s_x[i] = 0.0f;
    }
  } else {  // exact tie ranking, lowest-index-first (jax.lax.top_k stable)
    for (int r = 0; r < 16; ++r) {
      const int i = r * 256 + tid;
      const bool eq = ((__float_as_uint(s_x[i]) & 0x7fffffffu) == t_abs);
      const unsigned long long m = __ballot(eq);
      if (lane == 0) s_cmask[r * 4 + wave] = m;
    }
    __syncthreads();
    if (tid < 64) {
      const unsigned int cnt = (unsigned int)__popcll(s_cmask[tid]);
      unsigned int inc = cnt;
#pragma unroll
      for (int off = 1; off < 64; off <<= 1) {
        const unsigned int v = __shfl_up(inc, off, 64);
        if (tid >= off) inc += v;
      }
      s_cbase[tid] = inc - cnt;
    }
    __syncthreads();
    for (int r = 0; r < 16; ++r) {
      const int i = r * 256 + tid;
      const unsigned int ub = __float_as_uint(s_x[i]) & 0x7fffffffu;
      bool sel = (ub > t_abs);
      if (ub == t_abs) {
        const unsigned long long below =
            s_cmask[r * 4 + wave] & ((1ull << lane) - 1ull);
        sel = (s_cbase[r * 4 + wave] + (unsigned int)__popcll(below)) < need;
      }
      if (!sel) s_x[i] = 0.0f;
    }
  }
  __syncthreads();

  // ---- matvec: wave -> one W row, float4 stream, shuffle reduce ----
  float acc = 0.0f;
  {
    const float4 v0 = s_x4[0 * 64 + lane];
    acc += w0.x * v0.x + w0.y * v0.y + w0.z * v0.z + w0.w * v0.w;
    const float4 v1 = s_x4[1 * 64 + lane];
    acc += w1.x * v1.x + w1.y * v1.y + w1.z * v1.z + w1.w * v1.w;
    const float4 v2 = s_x4[2 * 64 + lane];
    acc += w2.x * v2.x + w2.y * v2.y + w2.z * v2.z + w2.w * v2.w;
    const float4 v3 = s_x4[3 * 64 + lane];
    acc += w3.x * v3.x + w3.y * v3.y + w3.z * v3.z + w3.w * v3.w;
  }
#pragma unroll
  for (int it = PF; it < N_IN / 256; ++it) {  // remaining 12 iterations
    const float4 w = wr4[it * 64 + lane];
    const float4 xv = s_x4[it * 64 + lane];
    acc += w.x * xv.x + w.y * xv.y + w.z * xv.z + w.w * xv.w;
  }

#pragma unroll
  for (int off = 32; off >= 1; off >>= 1) acc += __shfl_down(acc, off, 64);

  if (lane == 0) out[row] = acc + bias[row];
}

extern "C" void kernel_launch(void* const* d_in, const int* in_sizes, int n_in,
                              void* d_out, int out_size, void* d_ws,
                              size_t ws_size, hipStream_t stream) {
  const float* x    = (const float*)d_in[0];   // (1,1,4096) f32
  const float* W    = (const float*)d_in[1];   // (14336,4096) f32
  const float* bias = (const float*)d_in[2];   // (14336,) f32
  float* out = (float*)d_out;                  // (1,1,14336) f32

  fused_topk_matvec_kernel<<<N_OUT / 4, 256, 0, stream>>>(x, W, bias, out);
}

// Round 4
// 54.839 us; speedup vs baseline: 1.8701x; 1.8701x over previous
//
#include <hip/hip_runtime.h>
#include <hip/hip_bf16.h>

#define N_IN 4096
#define N_OUT 14336
#define TOPK 1228            // int(4096 * 0.3)

// ---------------------------------------------------------------------------
// Kernel A: threshold = TOPK-th largest |x| via 4-pass radix select on the
// positive-float bit pattern (order-preserving). Single block, 1024 threads.
// vs round 2: the 256-wide Hillis-Steele scan (16 barriers/pass) is replaced
// by a single-wave shfl suffix-scan over 4 bins/lane (3 barriers/pass),
// validated in round 3. Ballot-aggregated histogram kills LDS atomic
// same-address contention (N(0,1) concentrates pass-3 into ~7 bins).
// Writes x_masked (non-topk zeroed) to workspace.
// ---------------------------------------------------------------------------
__global__ __launch_bounds__(1024) void topk_mask_kernel(
    const float* __restrict__ x, float* __restrict__ x_masked) {
  __shared__ unsigned int s_abs[N_IN];                  // 16 KB
  __shared__ unsigned int s_hist[256];
  __shared__ unsigned int s_pk[4];                      // prefix, krem, eqc
  __shared__ unsigned long long s_cmask[N_IN / 64];     // tie path
  __shared__ unsigned int s_cbase[N_IN / 64];

  const int tid = threadIdx.x;
  const int lane = tid & 63;

#pragma unroll
  for (int it = 0; it < N_IN / 1024; ++it) {
    const int i = it * 1024 + tid;
    s_abs[i] = __float_as_uint(x[i]) & 0x7fffffffu;
  }
  if (tid == 0) { s_pk[0] = 0u; s_pk[1] = TOPK; }
  __syncthreads();

  // Radix select, MSB byte -> LSB byte.
  for (int pass = 3; pass >= 0; --pass) {
    const unsigned int prefix = s_pk[0];
    const unsigned int krem = s_pk[1];
    if (tid < 256) s_hist[tid] = 0u;
    __syncthreads();

    const int shift = pass * 8;
    const unsigned int maskAbove =
        (pass == 3) ? 0u : (0xFFFFFFFFu << (shift + 8));

    // Ballot-aggregated histogram: one atomic per distinct bucket per wave.
#pragma unroll
    for (int it = 0; it < N_IN / 1024; ++it) {
      const int i = it * 1024 + tid;
      const unsigned int b = s_abs[i];
      const bool active = ((b & maskAbove) == prefix);
      const unsigned int bucket = (b >> shift) & 0xFFu;
      unsigned long long m = __ballot(active);
#pragma unroll
      for (int bit = 0; bit < 8; ++bit) {
        const unsigned long long vote =
            __ballot(active && ((bucket >> bit) & 1u));
        m &= ((bucket >> bit) & 1u) ? vote : ~vote;
      }
      if (active) {
        const int leader = __ffsll((unsigned long long)m) - 1;
        if (lane == leader)
          atomicAdd(&s_hist[bucket], (unsigned int)__popcll(m));
      }
    }
    __syncthreads();

    // Wave 0: 4 bins/lane + shfl suffix-scan; unique winner updates s_pk.
    if (tid < 64) {
      const unsigned int h0 = s_hist[tid * 4 + 0];
      const unsigned int h1 = s_hist[tid * 4 + 1];
      const unsigned int h2 = s_hist[tid * 4 + 2];
      const unsigned int h3 = s_hist[tid * 4 + 3];
      const unsigned int s = h0 + h1 + h2 + h3;
      unsigned int inc = s;
#pragma unroll
      for (int off = 1; off < 64; off <<= 1) {
        const unsigned int v = __shfl_down(inc, off, 64);
        if (tid + off < 64) inc += v;
      }
      const unsigned int U = inc - s;  // sum over lanes > tid
      const unsigned int C3 = U + h3;
      const unsigned int C2 = C3 + h2;
      const unsigned int C1 = C2 + h1;
      const unsigned int C0 = C1 + h0;
      const unsigned int Carr[4] = {C0, C1, C2, C3};
      const unsigned int Sarr[4] = {C1, C2, C3, U};
      const unsigned int hv[4] = {h0, h1, h2, h3};
#pragma unroll
      for (int j = 0; j < 4; ++j) {
        if (Sarr[j] < krem && krem <= Carr[j]) {
          s_pk[0] = prefix | ((unsigned int)(tid * 4 + j) << shift);
          s_pk[1] = krem - Sarr[j];
          s_pk[2] = hv[j];
        }
      }
    }
    __syncthreads();
  }

  const unsigned int t_abs = s_pk[0];  // bits of TOPK-th largest |x|
  const unsigned int need = s_pk[1];   // # of ==t_abs elems to take (>=1)
  const unsigned int eqc = s_pk[2];    // total # of elems ==t_abs

  if (eqc == need) {  // fast path: no tie ranking needed (overwhelming case)
#pragma unroll
    for (int it = 0; it < N_IN / 1024; ++it) {
      const int i = it * 1024 + tid;
      x_masked[i] = (s_abs[i] >= t_abs) ? x[i] : 0.0f;
    }
  } else {  // exact tie ranking, lowest-index-first (jax.lax.top_k stable)
#pragma unroll
    for (int it = 0; it < N_IN / 1024; ++it) {
      const int i = it * 1024 + tid;
      const bool eq = (s_abs[i] == t_abs);
      const unsigned long long m = __ballot(eq);
      if (lane == 0) s_cmask[i >> 6] = m;
    }
    __syncthreads();
    if (tid < 64) {
      const unsigned int cnt = (unsigned int)__popcll(s_cmask[tid]);
      unsigned int inc = cnt;
#pragma unroll
      for (int off = 1; off < 64; off <<= 1) {
        const unsigned int v = __shfl_up(inc, off, 64);
        if (lane >= off) inc += v;
      }
      s_cbase[tid] = inc - cnt;
    }
    __syncthreads();
#pragma unroll
    for (int it = 0; it < N_IN / 1024; ++it) {
      const int i = it * 1024 + tid;
      const unsigned int b = s_abs[i];
      bool sel = (b > t_abs);
      if (b == t_abs) {
        const unsigned long long below =
            s_cmask[i >> 6] & ((1ull << lane) - 1ull);
        sel = (s_cbase[i >> 6] + (unsigned int)__popcll(below)) < need;
      }
      x_masked[i] = sel ? x[i] : 0.0f;
    }
  }
}

// ---------------------------------------------------------------------------
// Kernel B: out[o] = dot(x_masked, W[o,:]) + bias[o].
// 256 threads = 4 waves per block, one output row per wave.
// W streamed as coalesced float4; 4 independent accumulators for FMA ILP.
// ---------------------------------------------------------------------------
__global__ __launch_bounds__(256) void masked_matvec_kernel(
    const float* __restrict__ xm, const float* __restrict__ W,
    const float* __restrict__ bias, float* __restrict__ out) {
  __shared__ __align__(16) float s_x[N_IN];  // 16 KB

  const int tid = threadIdx.x;
  for (int i = tid; i < N_IN; i += 256) s_x[i] = xm[i];
  __syncthreads();

  const int wave = tid >> 6;
  const int lane = tid & 63;
  const int row = blockIdx.x * 4 + wave;
  const float4* __restrict__ wr4 =
      reinterpret_cast<const float4*>(W + (size_t)row * N_IN);
  const float4* s_x4 = reinterpret_cast<const float4*>(s_x);

  float a0 = 0.0f, a1 = 0.0f, a2 = 0.0f, a3 = 0.0f;
#pragma unroll
  for (int it = 0; it < 4; ++it) {  // 16 float4 loads, 4 indep FMA chains
    const int b = it * 4 * 64 + lane;
    const float4 w0 = wr4[b + 0 * 64];
    const float4 w1 = wr4[b + 1 * 64];
    const float4 w2 = wr4[b + 2 * 64];
    const float4 w3 = wr4[b + 3 * 64];
    const float4 v0 = s_x4[b + 0 * 64];
    const float4 v1 = s_x4[b + 1 * 64];
    const float4 v2 = s_x4[b + 2 * 64];
    const float4 v3 = s_x4[b + 3 * 64];
    a0 += w0.x * v0.x + w0.y * v0.y + w0.z * v0.z + w0.w * v0.w;
    a1 += w1.x * v1.x + w1.y * v1.y + w1.z * v1.z + w1.w * v1.w;
    a2 += w2.x * v2.x + w2.y * v2.y + w2.z * v2.z + w2.w * v2.w;
    a3 += w3.x * v3.x + w3.y * v3.y + w3.z * v3.z + w3.w * v3.w;
  }
  float acc = (a0 + a1) + (a2 + a3);

#pragma unroll
  for (int off = 32; off >= 1; off >>= 1) acc += __shfl_down(acc, off, 64);

  if (lane == 0) out[row] = acc + bias[row];
}

extern "C" void kernel_launch(void* const* d_in, const int* in_sizes, int n_in,
                              void* d_out, int out_size, void* d_ws,
                              size_t ws_size, hipStream_t stream) {
  const float* x    = (const float*)d_in[0];   // (1,1,4096) f32
  const float* W    = (const float*)d_in[1];   // (14336,4096) f32
  const float* bias = (const float*)d_in[2];   // (14336,) f32
  float* out = (float*)d_out;                  // (1,1,14336) f32
  float* xm  = (float*)d_ws;                   // 4096 f32 scratch

  topk_mask_kernel<<<1, 1024, 0, stream>>>(x, xm);
  masked_matvec_kernel<<<N_OUT / 4, 256, 0, stream>>>(xm, W, bias, out);
}

// Round 6
// 52.229 us; speedup vs baseline: 1.9635x; 1.0500x over previous
//
#include <hip/hip_runtime.h>
#include <hip/hip_bf16.h>

#define N_IN 4096
#define N_OUT 14336
#define TOPK 1228            // int(4096 * 0.3)

// ---------------------------------------------------------------------------
// Kernel A: threshold = TOPK-th largest |x| via 4-pass radix select on the
// positive-float bit pattern (order-preserving). Single block, 1024 threads.
// Ballot-aggregated histogram + single-wave shfl suffix-scan (3 barriers per
// pass). Writes x_masked (non-topk zeroed) to workspace. ~2-3 us.
// ---------------------------------------------------------------------------
__global__ __launch_bounds__(1024) void topk_mask_kernel(
    const float* __restrict__ x, float* __restrict__ x_masked) {
  __shared__ unsigned int s_abs[N_IN];                  // 16 KB
  __shared__ unsigned int s_hist[256];
  __shared__ unsigned int s_pk[4];                      // prefix, krem, eqc
  __shared__ unsigned long long s_cmask[N_IN / 64];     // tie path
  __shared__ unsigned int s_cbase[N_IN / 64];

  const int tid = threadIdx.x;
  const int lane = tid & 63;

#pragma unroll
  for (int it = 0; it < N_IN / 1024; ++it) {
    const int i = it * 1024 + tid;
    s_abs[i] = __float_as_uint(x[i]) & 0x7fffffffu;
  }
  if (tid == 0) { s_pk[0] = 0u; s_pk[1] = TOPK; }
  __syncthreads();

  // Radix select, MSB byte -> LSB byte.
  for (int pass = 3; pass >= 0; --pass) {
    const unsigned int prefix = s_pk[0];
    const unsigned int krem = s_pk[1];
    if (tid < 256) s_hist[tid] = 0u;
    __syncthreads();

    const int shift = pass * 8;
    const unsigned int maskAbove =
        (pass == 3) ? 0u : (0xFFFFFFFFu << (shift + 8));

    // Ballot-aggregated histogram: one atomic per distinct bucket per wave.
#pragma unroll
    for (int it = 0; it < N_IN / 1024; ++it) {
      const int i = it * 1024 + tid;
      const unsigned int b = s_abs[i];
      const bool active = ((b & maskAbove) == prefix);
      const unsigned int bucket = (b >> shift) & 0xFFu;
      unsigned long long m = __ballot(active);
#pragma unroll
      for (int bit = 0; bit < 8; ++bit) {
        const unsigned long long vote =
            __ballot(active && ((bucket >> bit) & 1u));
        m &= ((bucket >> bit) & 1u) ? vote : ~vote;
      }
      if (active) {
        const int leader = __ffsll((unsigned long long)m) - 1;
        if (lane == leader)
          atomicAdd(&s_hist[bucket], (unsigned int)__popcll(m));
      }
    }
    __syncthreads();

    // Wave 0: 4 bins/lane + shfl suffix-scan; unique winner updates s_pk.
    if (tid < 64) {
      const unsigned int h0 = s_hist[tid * 4 + 0];
      const unsigned int h1 = s_hist[tid * 4 + 1];
      const unsigned int h2 = s_hist[tid * 4 + 2];
      const unsigned int h3 = s_hist[tid * 4 + 3];
      const unsigned int s = h0 + h1 + h2 + h3;
      unsigned int inc = s;
#pragma unroll
      for (int off = 1; off < 64; off <<= 1) {
        const unsigned int v = __shfl_down(inc, off, 64);
        if (tid + off < 64) inc += v;
      }
      const unsigned int U = inc - s;  // sum over lanes > tid
      const unsigned int C3 = U + h3;
      const unsigned int C2 = C3 + h2;
      const unsigned int C1 = C2 + h1;
      const unsigned int C0 = C1 + h0;
      const unsigned int Carr[4] = {C0, C1, C2, C3};
      const unsigned int Sarr[4] = {C1, C2, C3, U};
      const unsigned int hv[4] = {h0, h1, h2, h3};
#pragma unroll
      for (int j = 0; j < 4; ++j) {
        if (Sarr[j] < krem && krem <= Carr[j]) {
          s_pk[0] = prefix | ((unsigned int)(tid * 4 + j) << shift);
          s_pk[1] = krem - Sarr[j];
          s_pk[2] = hv[j];
        }
      }
    }
    __syncthreads();
  }

  const unsigned int t_abs = s_pk[0];  // bits of TOPK-th largest |x|
  const unsigned int need = s_pk[1];   // # of ==t_abs elems to take (>=1)
  const unsigned int eqc = s_pk[2];    // total # of elems ==t_abs

  if (eqc == need) {  // fast path: no tie ranking needed (overwhelming case)
#pragma unroll
    for (int it = 0; it < N_IN / 1024; ++it) {
      const int i = it * 1024 + tid;
      x_masked[i] = (s_abs[i] >= t_abs) ? x[i] : 0.0f;
    }
  } else {  // exact tie ranking, lowest-index-first (jax.lax.top_k stable)
#pragma unroll
    for (int it = 0; it < N_IN / 1024; ++it) {
      const int i = it * 1024 + tid;
      const bool eq = (s_abs[i] == t_abs);
      const unsigned long long m = __ballot(eq);
      if (lane == 0) s_cmask[i >> 6] = m;
    }
    __syncthreads();
    if (tid < 64) {
      const unsigned int cnt = (unsigned int)__popcll(s_cmask[tid]);
      unsigned int inc = cnt;
#pragma unroll
      for (int off = 1; off < 64; off <<= 1) {
        const unsigned int v = __shfl_up(inc, off, 64);
        if (lane >= off) inc += v;
      }
      s_cbase[tid] = inc - cnt;
    }
    __syncthreads();
#pragma unroll
    for (int it = 0; it < N_IN / 1024; ++it) {
      const int i = it * 1024 + tid;
      const unsigned int b = s_abs[i];
      bool sel = (b > t_abs);
      if (b == t_abs) {
        const unsigned long long below =
            s_cmask[i >> 6] & ((1ull << lane) - 1ull);
        sel = (s_cbase[i >> 6] + (unsigned int)__popcll(below)) < need;
      }
      x_masked[i] = sel ? x[i] : 0.0f;
    }
  }
}

// ---------------------------------------------------------------------------
// Kernel B: out[o] = dot(x_masked, W[o,:]) + bias[o].
// 256 threads = 4 waves per block, one output row per wave.
//
// Column PHASE-STAGGER: row r walks its 16 column-chunks starting at chunk
// (r & 15), wrapping — breaks column-phase-lock across ~8K concurrent waves
// on rows spaced exactly 16 KB apart (suspected HBM channel / L2-set
// imbalance behind the ~75%-of-peak plateau).
// First 4 (rotated) W loads issued before the staging barrier.
// FIX vs round 5: stage ALL of s_x (4 float4 per thread; round 5 staged
// only 1/4 of it -> garbage).
// ---------------------------------------------------------------------------
__global__ __launch_bounds__(256) void masked_matvec_kernel(
    const float* __restrict__ xm, const float* __restrict__ W,
    const float* __restrict__ bias, float* __restrict__ out) {
  __shared__ __align__(16) float s_x[N_IN];  // 16 KB

  const int tid = threadIdx.x;
  const int wave = tid >> 6;
  const int lane = tid & 63;
  const int row = blockIdx.x * 4 + wave;
  const int phase = row & 15;

  const float4* __restrict__ wr4 =
      reinterpret_cast<const float4*>(W + (size_t)row * N_IN);
  const float4* __restrict__ x4 = reinterpret_cast<const float4*>(xm);
  const float4* s_x4 = reinterpret_cast<const float4*>(s_x);
  float4* s_x4w = reinterpret_cast<float4*>(s_x);

  // Prefetch the first 4 rotated W chunks before the staging barrier.
  const int c0 = phase;
  const int c1 = (phase + 1) & 15;
  const int c2 = (phase + 2) & 15;
  const int c3 = (phase + 3) & 15;
  const float4 w0 = wr4[c0 * 64 + lane];
  const float4 w1 = wr4[c1 * 64 + lane];
  const float4 w2 = wr4[c2 * 64 + lane];
  const float4 w3 = wr4[c3 * 64 + lane];

  // Stage ALL of x into LDS: 1024 float4s, 256 threads -> 4 each.
#pragma unroll
  for (int it = 0; it < 4; ++it)
    s_x4w[it * 256 + tid] = x4[it * 256 + tid];
  __syncthreads();

  float a0, a1, a2, a3;
  {
    const float4 v0 = s_x4[c0 * 64 + lane];
    const float4 v1 = s_x4[c1 * 64 + lane];
    const float4 v2 = s_x4[c2 * 64 + lane];
    const float4 v3 = s_x4[c3 * 64 + lane];
    a0 = w0.x * v0.x + w0.y * v0.y + w0.z * v0.z + w0.w * v0.w;
    a1 = w1.x * v1.x + w1.y * v1.y + w1.z * v1.z + w1.w * v1.w;
    a2 = w2.x * v2.x + w2.y * v2.y + w2.z * v2.z + w2.w * v2.w;
    a3 = w3.x * v3.x + w3.y * v3.y + w3.z * v3.z + w3.w * v3.w;
  }

#pragma unroll
  for (int it = 4; it < 16; it += 4) {  // remaining 12 chunks, rotated
    const int b0 = ((phase + it + 0) & 15) * 64 + lane;
    const int b1 = ((phase + it + 1) & 15) * 64 + lane;
    const int b2 = ((phase + it + 2) & 15) * 64 + lane;
    const int b3 = ((phase + it + 3) & 15) * 64 + lane;
    const float4 u0 = wr4[b0];
    const float4 u1 = wr4[b1];
    const float4 u2 = wr4[b2];
    const float4 u3 = wr4[b3];
    const float4 v0 = s_x4[b0];
    const float4 v1 = s_x4[b1];
    const float4 v2 = s_x4[b2];
    const float4 v3 = s_x4[b3];
    a0 += u0.x * v0.x + u0.y * v0.y + u0.z * v0.z + u0.w * v0.w;
    a1 += u1.x * v1.x + u1.y * v1.y + u1.z * v1.z + u1.w * v1.w;
    a2 += u2.x * v2.x + u2.y * v2.y + u2.z * v2.z + u2.w * v2.w;
    a3 += u3.x * v3.x + u3.y * v3.y + u3.z * v3.z + u3.w * v3.w;
  }
  float acc = (a0 + a1) + (a2 + a3);

#pragma unroll
  for (int off = 32; off >= 1; off >>= 1) acc += __shfl_down(acc, off, 64);

  if (lane == 0) out[row] = acc + bias[row];
}

extern "C" void kernel_launch(void* const* d_in, const int* in_sizes, int n_in,
                              void* d_out, int out_size, void* d_ws,
                              size_t ws_size, hipStream_t stream) {
  const float* x    = (const float*)d_in[0];   // (1,1,4096) f32
  const float* W    = (const float*)d_in[1];   // (14336,4096) f32
  const float* bias = (const float*)d_in[2];   // (14336,) f32
  float* out = (float*)d_out;                  // (1,1,14336) f32
  float* xm  = (float*)d_ws;                   // 4096 f32 scratch

  topk_mask_kernel<<<1, 1024, 0, stream>>>(x, xm);
  masked_matvec_kernel<<<N_OUT / 4, 256, 0, stream>>>(xm, W, bias, out);
}

// Round 7
// 51.952 us; speedup vs baseline: 1.9740x; 1.0053x over previous
//
#include <hip/hip_runtime.h>
#include <hip/hip_bf16.h>

#define N_IN 4096
#define N_OUT 14336
#define TOPK 1228            // int(4096 * 0.3)

// ---------------------------------------------------------------------------
// Kernel A (unchanged from round 6): threshold = TOPK-th largest |x| via
// 4-pass radix select on the positive-float bit pattern. Single block, 1024
// threads. Ballot-aggregated histogram + single-wave shfl suffix-scan.
// Writes x_masked (non-topk zeroed) to workspace.
// ---------------------------------------------------------------------------
__global__ __launch_bounds__(1024) void topk_mask_kernel(
    const float* __restrict__ x, float* __restrict__ x_masked) {
  __shared__ unsigned int s_abs[N_IN];                  // 16 KB
  __shared__ unsigned int s_hist[256];
  __shared__ unsigned int s_pk[4];                      // prefix, krem, eqc
  __shared__ unsigned long long s_cmask[N_IN / 64];     // tie path
  __shared__ unsigned int s_cbase[N_IN / 64];

  const int tid = threadIdx.x;
  const int lane = tid & 63;

#pragma unroll
  for (int it = 0; it < N_IN / 1024; ++it) {
    const int i = it * 1024 + tid;
    s_abs[i] = __float_as_uint(x[i]) & 0x7fffffffu;
  }
  if (tid == 0) { s_pk[0] = 0u; s_pk[1] = TOPK; }
  __syncthreads();

  // Radix select, MSB byte -> LSB byte.
  for (int pass = 3; pass >= 0; --pass) {
    const unsigned int prefix = s_pk[0];
    const unsigned int krem = s_pk[1];
    if (tid < 256) s_hist[tid] = 0u;
    __syncthreads();

    const int shift = pass * 8;
    const unsigned int maskAbove =
        (pass == 3) ? 0u : (0xFFFFFFFFu << (shift + 8));

    // Ballot-aggregated histogram: one atomic per distinct bucket per wave.
#pragma unroll
    for (int it = 0; it < N_IN / 1024; ++it) {
      const int i = it * 1024 + tid;
      const unsigned int b = s_abs[i];
      const bool active = ((b & maskAbove) == prefix);
      const unsigned int bucket = (b >> shift) & 0xFFu;
      unsigned long long m = __ballot(active);
#pragma unroll
      for (int bit = 0; bit < 8; ++bit) {
        const unsigned long long vote =
            __ballot(active && ((bucket >> bit) & 1u));
        m &= ((bucket >> bit) & 1u) ? vote : ~vote;
      }
      if (active) {
        const int leader = __ffsll((unsigned long long)m) - 1;
        if (lane == leader)
          atomicAdd(&s_hist[bucket], (unsigned int)__popcll(m));
      }
    }
    __syncthreads();

    // Wave 0: 4 bins/lane + shfl suffix-scan; unique winner updates s_pk.
    if (tid < 64) {
      const unsigned int h0 = s_hist[tid * 4 + 0];
      const unsigned int h1 = s_hist[tid * 4 + 1];
      const unsigned int h2 = s_hist[tid * 4 + 2];
      const unsigned int h3 = s_hist[tid * 4 + 3];
      const unsigned int s = h0 + h1 + h2 + h3;
      unsigned int inc = s;
#pragma unroll
      for (int off = 1; off < 64; off <<= 1) {
        const unsigned int v = __shfl_down(inc, off, 64);
        if (tid + off < 64) inc += v;
      }
      const unsigned int U = inc - s;  // sum over lanes > tid
      const unsigned int C3 = U + h3;
      const unsigned int C2 = C3 + h2;
      const unsigned int C1 = C2 + h1;
      const unsigned int C0 = C1 + h0;
      const unsigned int Carr[4] = {C0, C1, C2, C3};
      const unsigned int Sarr[4] = {C1, C2, C3, U};
      const unsigned int hv[4] = {h0, h1, h2, h3};
#pragma unroll
      for (int j = 0; j < 4; ++j) {
        if (Sarr[j] < krem && krem <= Carr[j]) {
          s_pk[0] = prefix | ((unsigned int)(tid * 4 + j) << shift);
          s_pk[1] = krem - Sarr[j];
          s_pk[2] = hv[j];
        }
      }
    }
    __syncthreads();
  }

  const unsigned int t_abs = s_pk[0];  // bits of TOPK-th largest |x|
  const unsigned int need = s_pk[1];   // # of ==t_abs elems to take (>=1)
  const unsigned int eqc = s_pk[2];    // total # of elems ==t_abs

  if (eqc == need) {  // fast path: no tie ranking needed (overwhelming case)
#pragma unroll
    for (int it = 0; it < N_IN / 1024; ++it) {
      const int i = it * 1024 + tid;
      x_masked[i] = (s_abs[i] >= t_abs) ? x[i] : 0.0f;
    }
  } else {  // exact tie ranking, lowest-index-first (jax.lax.top_k stable)
#pragma unroll
    for (int it = 0; it < N_IN / 1024; ++it) {
      const int i = it * 1024 + tid;
      const bool eq = (s_abs[i] == t_abs);
      const unsigned long long m = __ballot(eq);
      if (lane == 0) s_cmask[i >> 6] = m;
    }
    __syncthreads();
    if (tid < 64) {
      const unsigned int cnt = (unsigned int)__popcll(s_cmask[tid]);
      unsigned int inc = cnt;
#pragma unroll
      for (int off = 1; off < 64; off <<= 1) {
        const unsigned int v = __shfl_up(inc, off, 64);
        if (lane >= off) inc += v;
      }
      s_cbase[tid] = inc - cnt;
    }
    __syncthreads();
#pragma unroll
    for (int it = 0; it < N_IN / 1024; ++it) {
      const int i = it * 1024 + tid;
      const unsigned int b = s_abs[i];
      bool sel = (b > t_abs);
      if (b == t_abs) {
        const unsigned long long below =
            s_cmask[i >> 6] & ((1ull << lane) - 1ull);
        sel = (s_cbase[i >> 6] + (unsigned int)__popcll(below)) < need;
      }
      x_masked[i] = sel ? x[i] : 0.0f;
    }
  }
}

// ---------------------------------------------------------------------------
// Kernel B: out[o] = dot(x_masked, W[o,:]) + bias[o].
// 256 threads = 4 waves; each wave owns TWO CONSECUTIVE rows (r0, r0+1),
// interleaved in the inner loop -> 8 outstanding float4 loads per wave and a
// 32 KB contiguous footprint per wave. Grid = 1792 = exactly 7 blocks/CU
// (all resident, single generation, no tail). Halves the number of
// concurrent DRAM row-streams vs 1-row-per-wave (8192 -> 4096), targeting
// the HBM row-buffer/bank-queue thrash suspected of capping us at ~5 TB/s.
// Phase-stagger retained per row-pair: phase = (r0>>1) & 15 covers all 16.
// ---------------------------------------------------------------------------
__global__ __launch_bounds__(256) void masked_matvec_kernel(
    const float* __restrict__ xm, const float* __restrict__ W,
    const float* __restrict__ bias, float* __restrict__ out) {
  __shared__ __align__(16) float s_x[N_IN];  // 16 KB

  const int tid = threadIdx.x;
  const int wave = tid >> 6;
  const int lane = tid & 63;
  const int r0 = blockIdx.x * 8 + wave * 2;  // rows r0 and r0+1
  const int phase = (r0 >> 1) & 15;

  const float4* __restrict__ w0r4 =
      reinterpret_cast<const float4*>(W + (size_t)r0 * N_IN);
  const float4* __restrict__ w1r4 =
      reinterpret_cast<const float4*>(W + (size_t)(r0 + 1) * N_IN);
  const float4* __restrict__ x4 = reinterpret_cast<const float4*>(xm);
  const float4* s_x4 = reinterpret_cast<const float4*>(s_x);
  float4* s_x4w = reinterpret_cast<float4*>(s_x);

  // Prefetch group 0 (4 chunks, both rows) before the staging barrier.
  const int c0 = phase;
  const int c1 = (phase + 1) & 15;
  const int c2 = (phase + 2) & 15;
  const int c3 = (phase + 3) & 15;
  const float4 p00 = w0r4[c0 * 64 + lane];
  const float4 p01 = w0r4[c1 * 64 + lane];
  const float4 p02 = w0r4[c2 * 64 + lane];
  const float4 p03 = w0r4[c3 * 64 + lane];
  const float4 p10 = w1r4[c0 * 64 + lane];
  const float4 p11 = w1r4[c1 * 64 + lane];
  const float4 p12 = w1r4[c2 * 64 + lane];
  const float4 p13 = w1r4[c3 * 64 + lane];

  // Stage ALL of x into LDS: 1024 float4s, 256 threads -> 4 each.
#pragma unroll
  for (int it = 0; it < 4; ++it)
    s_x4w[it * 256 + tid] = x4[it * 256 + tid];
  __syncthreads();

  float a00, a01, a02, a03, a10, a11, a12, a13;
  {
    const float4 v0 = s_x4[c0 * 64 + lane];
    const float4 v1 = s_x4[c1 * 64 + lane];
    const float4 v2 = s_x4[c2 * 64 + lane];
    const float4 v3 = s_x4[c3 * 64 + lane];
    a00 = p00.x * v0.x + p00.y * v0.y + p00.z * v0.z + p00.w * v0.w;
    a01 = p01.x * v1.x + p01.y * v1.y + p01.z * v1.z + p01.w * v1.w;
    a02 = p02.x * v2.x + p02.y * v2.y + p02.z * v2.z + p02.w * v2.w;
    a03 = p03.x * v3.x + p03.y * v3.y + p03.z * v3.z + p03.w * v3.w;
    a10 = p10.x * v0.x + p10.y * v0.y + p10.z * v0.z + p10.w * v0.w;
    a11 = p11.x * v1.x + p11.y * v1.y + p11.z * v1.z + p11.w * v1.w;
    a12 = p12.x * v2.x + p12.y * v2.y + p12.z * v2.z + p12.w * v2.w;
    a13 = p13.x * v3.x + p13.y * v3.y + p13.z * v3.z + p13.w * v3.w;
  }

#pragma unroll
  for (int g = 1; g < 4; ++g) {  // remaining 12 chunks per row, rotated
    const int b0 = ((phase + g * 4 + 0) & 15) * 64 + lane;
    const int b1 = ((phase + g * 4 + 1) & 15) * 64 + lane;
    const int b2 = ((phase + g * 4 + 2) & 15) * 64 + lane;
    const int b3 = ((phase + g * 4 + 3) & 15) * 64 + lane;
    const float4 u00 = w0r4[b0];
    const float4 u01 = w0r4[b1];
    const float4 u02 = w0r4[b2];
    const float4 u03 = w0r4[b3];
    const float4 u10 = w1r4[b0];
    const float4 u11 = w1r4[b1];
    const float4 u12 = w1r4[b2];
    const float4 u13 = w1r4[b3];
    const float4 v0 = s_x4[b0];
    const float4 v1 = s_x4[b1];
    const float4 v2 = s_x4[b2];
    const float4 v3 = s_x4[b3];
    a00 += u00.x * v0.x + u00.y * v0.y + u00.z * v0.z + u00.w * v0.w;
    a01 += u01.x * v1.x + u01.y * v1.y + u01.z * v1.z + u01.w * v1.w;
    a02 += u02.x * v2.x + u02.y * v2.y + u02.z * v2.z + u02.w * v2.w;
    a03 += u03.x * v3.x + u03.y * v3.y + u03.z * v3.z + u03.w * v3.w;
    a10 += u10.x * v0.x + u10.y * v0.y + u10.z * v0.z + u10.w * v0.w;
    a11 += u11.x * v1.x + u11.y * v1.y + u11.z * v1.z + u11.w * v1.w;
    a12 += u12.x * v2.x + u12.y * v2.y + u12.z * v2.z + u12.w * v2.w;
    a13 += u13.x * v3.x + u13.y * v3.y + u13.z * v3.z + u13.w * v3.w;
  }
  float acc0 = (a00 + a01) + (a02 + a03);
  float acc1 = (a10 + a11) + (a12 + a13);

#pragma unroll
  for (int off = 32; off >= 1; off >>= 1) {
    acc0 += __shfl_down(acc0, off, 64);
    acc1 += __shfl_down(acc1, off, 64);
  }

  if (lane == 0) {
    out[r0] = acc0 + bias[r0];
    out[r0 + 1] = acc1 + bias[r0 + 1];
  }
}

extern "C" void kernel_launch(void* const* d_in, const int* in_sizes, int n_in,
                              void* d_out, int out_size, void* d_ws,
                              size_t ws_size, hipStream_t stream) {
  const float* x    = (const float*)d_in[0];   // (1,1,4096) f32
  const float* W    = (const float*)d_in[1];   // (14336,4096) f32
  const float* bias = (const float*)d_in[2];   // (14336,) f32
  float* out = (float*)d_out;                  // (1,1,14336) f32
  float* xm  = (float*)d_ws;                   // 4096 f32 scratch

  topk_mask_kernel<<<1, 1024, 0, stream>>>(x, xm);
  masked_matvec_kernel<<<N_OUT / 8, 256, 0, stream>>>(xm, W, bias, out);
}